// Round 14
// baseline (282.255 us; speedup 1.0000x reference)
//
#include <hip/hip_runtime.h>
#include <math.h>

typedef _Float16 f16;
typedef _Float16 f16x2 __attribute__((ext_vector_type(2)));
typedef _Float16 f16x4 __attribute__((ext_vector_type(4)));
typedef _Float16 f16x8 __attribute__((ext_vector_type(8)));
typedef float f32x4 __attribute__((ext_vector_type(4)));

#if defined(__has_builtin)
#if __has_builtin(__builtin_amdgcn_fdot2)
#define USE_FDOT2 1
#endif
#if __has_builtin(__builtin_amdgcn_exp2f)
#define USE_EXP2 1
#endif
#endif

__device__ __forceinline__ float fdot2f(f16x2 a, f16x2 b, float c) {
#ifdef USE_FDOT2
    return __builtin_amdgcn_fdot2(a, b, c, false);
#else
    return c + (float)a.x * (float)b.x + (float)a.y * (float)b.y;
#endif
}
__device__ __forceinline__ float exp2fast(float a) {
#ifdef USE_EXP2
    return __builtin_amdgcn_exp2f(a);
#else
    return exp2f(a);
#endif
}

namespace {
// 192 real kv rows; 320 zero rows folded analytically (pz, multiplicity 320).
constexpr int NKV = 192;
constexpr int XLS = 65;    // f32/row x-stage stride (bank: (lane+f)%32, conflict-free)
constexpr int KS  = 40;    // f16/row k LDS
constexpr int QLS = 40;    // f16/row q LDS
constexpr int VTS = 200;   // f16/row V-transposed [32 ch][192 kv + pad]
constexpr int PSW = 40;    // f16/row per-wave P chunk [32][40]
// Phase A: xl f32[192][65] = 49920 B at offset 0.
// Phase B+ overlays (xl dead after LN reads):
constexpr int OFF_KL = 0;            // 192*40*2 = 15360
constexpr int OFF_VT = 15360;        // 32*200*2 = 12800 -> 28160
constexpr int OFF_QL = 28160;        // 128*40*2 = 10240 -> 38400
constexpr int OFF_PW = 38400;        // 4*32*40*2 = 10240 -> 48640
constexpr int OFF_LI = 48640;        // f32[128] -> 49152
constexpr int OFF_PZ = 49152;        // f32[128] -> 49664
constexpr int ATT_LDS = 49920;       // x3 = 149760 < 160K -> 3 blocks/CU
constexpr float C1  = 0.2550600f;    // (1/sqrt(32)) * log2(e)
constexpr float CZN = -5.7707801f;   // -4*log2(e)  (fixed softmax shift; scores tiny)
constexpr float CZV = 2.5511480f;    // CZN + log2(320)

// packed-f16 weights: P[out][in/2] f16x2 pairs (row o = 64 contiguous f16 = W[:,o])
constexpr int OFF_WQ  = 0;
constexpr int OFF_WKV = 4096;
constexpr int OFF_WO  = 12288;
constexpr int OFF_W1  = 16384;
constexpr int OFF_W2  = 20480;
constexpr int NPAIRS  = 24576;
}

__device__ f16x2 g_wpack[NPAIRS];

// ---------------- Kernel 0: pack GEMV weights to f16x2 ----------------
__global__ void k_conv(const float* __restrict__ Wq, const float* __restrict__ Wkv,
                       const float* __restrict__ Wo, const float* __restrict__ W1,
                       const float* __restrict__ W2) {
    const int i = blockIdx.x * 256 + threadIdx.x;
    const float* src; int inp, out, base;
    if (i < OFF_WKV)     { src = Wq;  inp = 32; out = 128; base = OFF_WQ;  }
    else if (i < OFF_WO) { src = Wkv; inp = 32; out = 256; base = OFF_WKV; }
    else if (i < OFF_W1) { src = Wo;  inp = 64; out = 64;  base = OFF_WO;  }
    else if (i < OFF_W2) { src = W1;  inp = 32; out = 128; base = OFF_W1;  }
    else                 { src = W2;  inp = 64; out = 64;  base = OFF_W2;  }
    const int li = i - base;
    const int o = li / inp, p = li % inp;
    g_wpack[i] = (f16x2){(f16)src[(2*p) * out + o], (f16)src[(2*p+1) * out + o]};
}

// acc[j] += h2 . Wrow[j] with VECTORIZED 16B weight loads (8x f16x8 per output row).
// Fully unrolled, all h2 indices static (rule #20).
template<int NACC>
__device__ __forceinline__ void projv(const f16x2* __restrict__ h2,
                                      const f16* __restrict__ Wrow,
                                      float* __restrict__ acc) {
    #pragma unroll
    for (int j = 0; j < NACC; ++j) {
        const f16x8* wr = (const f16x8*)(Wrow + j * 64);
        float t = acc[j];
        #pragma unroll
        for (int m = 0; m < 8; ++m) {
            const f16x8 wm = wr[m];
            t = fdot2f(h2[4*m+0], (f16x2){wm[0], wm[1]}, t);
            t = fdot2f(h2[4*m+1], (f16x2){wm[2], wm[3]}, t);
            t = fdot2f(h2[4*m+2], (f16x2){wm[4], wm[5]}, t);
            t = fdot2f(h2[4*m+3], (f16x2){wm[6], wm[7]}, t);
        }
        acc[j] = t;
    }
}

// ---------------- Kernel 1: per-(window,head) attention via MFMA ----------------
__global__ __launch_bounds__(256, 3) void k_att(
    const float* __restrict__ x,
    const float* __restrict__ ln1_s, const float* __restrict__ ln1_b,
    const float* __restrict__ bkv,
    f16* __restrict__ o_out)
{
    __shared__ __align__(16) char smem[ATT_LDS];
    float* xl = (float*)smem;                 // Phase A: [192][XLS] f32
    f16* kl   = (f16*)(smem + OFF_KL);        // Phase B+ overlays
    f16* vt   = (f16*)(smem + OFF_VT);
    f16* ql   = (f16*)(smem + OFF_QL);
    float* linv = (float*)(smem + OFF_LI);
    float* pzn  = (float*)(smem + OFF_PZ);

    const int tid  = threadIdx.x;
    const int bid  = blockIdx.x;
    const int w    = bid & 511;
    const int head = bid >> 9;
    const int cb   = head * 32;
    const int n    = w & 255;
    const int t    = w >> 8;

    const f16* WqF  = (const f16*)(g_wpack + OFF_WQ);
    const f16* WkvF = (const f16*)(g_wpack + OFF_WKV);

    // ---- Phase A: cooperative COALESCED x -> LDS. The 192 kv rows are 12
    // contiguous 4KB segments (16 tokens x 64 f32 each). r13 fix: previous
    // per-thread row loads hit 64 cache lines per instruction (256B stride).
    #pragma unroll
    for (int s12 = 0; s12 < 12; ++s12) {
        const int v_ = s12 / 6;
        const int t2 = (s12 % 6) + ((t == 0) ? 2 : 0);
        int tsrc, tt;
        if (t2 < 2)      { tsrc = t - 1; tt = t2 + 2; }
        else if (t2 < 6) { tsrc = t;     tt = t2 - 2; }
        else             { tsrc = t + 1; tt = t2 - 6; }
        const size_t fbase = ((size_t)(v_ * 8 + tsrc * 4 + tt) * 1024 + n * 4) * 256;
        const float4 val = *(const float4*)(x + fbase + tid * 4);
        float* dst = xl + (s12 * 16 + (tid >> 4)) * XLS + (tid & 15) * 4;
        dst[0] = val.x; dst[1] = val.y; dst[2] = val.z; dst[3] = val.w;
    }
    __syncthreads();

    // ---- Phase B: LN from LDS (conflict-free scalar reads), h2 in regs
    f16x2 h2[32];
    int tsrc_own = -1;
    int v_own = 0, tt_own = 0, nn_own = 0, dd_own = 0;
    if (tid < NKV) {
        v_own = (tid >= 96) ? 1 : 0;
        const int rem = tid - v_own * 96;
        const int t2i = rem >> 4;
        nn_own = (rem >> 2) & 3; dd_own = rem & 3;
        const int t2 = t2i + ((t == 0) ? 2 : 0);
        if (t2 < 2)      { tsrc_own = t - 1; tt_own = t2 + 2; }
        else if (t2 < 6) { tsrc_own = t;     tt_own = t2 - 2; }
        else             { tsrc_own = t + 1; tt_own = t2 - 6; }
        const float* xr = xl + tid * XLS;
        float s = 0.f, ss = 0.f;
        #pragma unroll
        for (int i = 0; i < 32; ++i) {
            const float a = xr[2*i], b = xr[2*i+1];
            s += a + b; ss += a*a + b*b;
            h2[i] = (f16x2){(f16)a, (f16)b};
        }
        const float mean = s * 0.015625f;
        const float rstd = rsqrtf(ss * 0.015625f - mean*mean + 1e-5f);
        #pragma unroll
        for (int i = 0; i < 32; ++i) {
            const float a0 = ((float)h2[i].x - mean) * rstd * ln1_s[2*i]   + ln1_b[2*i];
            const float a1 = ((float)h2[i].y - mean) * rstd * ln1_s[2*i+1] + ln1_b[2*i+1];
            h2[i] = (f16x2){(f16)a0, (f16)a1};
        }
    }
    __syncthreads();   // all xl reads done; kl/vt/ql may overlay

    // ---- Phase C: projections (weights from packed global, vectorized loads)
    if (tid < NKV) {
        #pragma unroll 1
        for (int which = 0; which < 2; ++which) {
            #pragma unroll 1
            for (int chunk = 0; chunk < 2; ++chunk) {
                const int ob = which * 128 + cb + chunk * 16;
                float acc[16];
                #pragma unroll
                for (int j = 0; j < 16; ++j) acc[j] = bkv[ob + j];
                projv<16>(h2, WkvF + ob * 64, acc);
                if (which == 0) {
                    f16x8 p0, p1;
                    #pragma unroll
                    for (int j = 0; j < 8; ++j) { p0[j] = (f16)acc[j]; p1[j] = (f16)acc[j + 8]; }
                    ((f16x8*)(kl + tid * KS + chunk * 16))[0] = p0;
                    ((f16x8*)(kl + tid * KS + chunk * 16 + 8))[0] = p1;
                } else {
                    #pragma unroll
                    for (int j = 0; j < 16; ++j)
                        vt[(chunk * 16 + j) * VTS + tid] = (f16)acc[j];
                }
            }
        }
        if (tsrc_own == t) {   // this kv row IS one of the window's 128 q tokens
            const int qr = v_own * 64 + tt_own * 16 + nn_own * 4 + dd_own;
            float q0[16], q1[16];
            #pragma unroll
            for (int j = 0; j < 16; ++j) { q0[j] = 0.f; q1[j] = 0.f; }
            projv<16>(h2, WqF + cb * 64, q0);
            projv<16>(h2, WqF + (cb + 16) * 64, q1);
            f16x8 pa, pb, pc, pd;
            #pragma unroll
            for (int j = 0; j < 8; ++j) {
                pa[j] = (f16)q0[j];     pb[j] = (f16)q0[j + 8];
                pc[j] = (f16)q1[j];     pd[j] = (f16)q1[j + 8];
            }
            ((f16x8*)(ql + qr * QLS +  0))[0] = pa;
            ((f16x8*)(ql + qr * QLS +  8))[0] = pb;
            ((f16x8*)(ql + qr * QLS + 16))[0] = pc;
            ((f16x8*)(ql + qr * QLS + 24))[0] = pd;
        }
    }
    __syncthreads();

    const int lane = tid & 63, wv = tid >> 6;
    const int lr = lane & 15, lg = lane >> 4;
    const int mA = wv * 32;                       // this wave's 32 output rows
    f16* Pw = (f16*)(smem + OFF_PW) + wv * 32 * PSW;   // per-wave P chunk [32][PSW]

    // per-row virtual zero-token weight (threads 0-127, one per q row)
    float pz = 0.f;
    if (tid < 128) {
        const f16x2* qr2 = (const f16x2*)(ql + tid * QLS);
        float sz = 0.f;
        #pragma unroll
        for (int j = 0; j < 16; ++j)
            sz += (float)qr2[j].x * bkv[cb + 2*j] + (float)qr2[j].y * bkv[cb + 2*j + 1];
        pz = exp2fast(fmaf(sz, C1, CZV));
    }

    f32x4 oc00 = {0.f,0.f,0.f,0.f}, oc01 = {0.f,0.f,0.f,0.f};
    f32x4 oc10 = {0.f,0.f,0.f,0.f}, oc11 = {0.f,0.f,0.f,0.f};
    float l_own = 0.f;
    const int prow = lane & 31, pcolh = lane >> 5;

    // ---- flash: 6 chunks of 32 kv; per-wave P chunk -> no block barriers inside
    #pragma unroll 1
    for (int kk = 0; kk < 6; ++kk) {
        #pragma unroll
        for (int mi = 0; mi < 2; ++mi) {
            const f16x8 af = *(const f16x8*)(ql + (mA + mi*16 + lr) * QLS + lg * 8);
            #pragma unroll
            for (int nt = 0; nt < 2; ++nt) {
                const f16x8 bf = *(const f16x8*)(kl + (kk*32 + nt*16 + lr) * KS + lg * 8);
                const f32x4 c = __builtin_amdgcn_mfma_f32_16x16x32_f16(af, bf, (f32x4){0.f,0.f,0.f,0.f}, 0, 0, 0);
                #pragma unroll
                for (int e = 0; e < 4; ++e)
                    Pw[(mi*16 + lg*4 + e) * PSW + nt*16 + lr] = (f16)exp2fast(fmaf(c[e], C1, CZN));
            }
        }
        const f16x8 a0 = *(const f16x8*)(Pw + lr * PSW + lg * 8);
        const f16x8 a1 = *(const f16x8*)(Pw + (16 + lr) * PSW + lg * 8);
        const f16x8 b0 = *(const f16x8*)(vt + lr * VTS + kk*32 + lg*8);
        const f16x8 b1 = *(const f16x8*)(vt + (16 + lr) * VTS + kk*32 + lg*8);
        oc00 = __builtin_amdgcn_mfma_f32_16x16x32_f16(a0, b0, oc00, 0, 0, 0);
        oc01 = __builtin_amdgcn_mfma_f32_16x16x32_f16(a0, b1, oc01, 0, 0, 0);
        oc10 = __builtin_amdgcn_mfma_f32_16x16x32_f16(a1, b0, oc10, 0, 0, 0);
        oc11 = __builtin_amdgcn_mfma_f32_16x16x32_f16(a1, b1, oc11, 0, 0, 0);
        {
            const f16x2* pr = (const f16x2*)(Pw + prow * PSW + pcolh * 16);
            const f16x2 ones = (f16x2){(f16)1.f, (f16)1.f};
            float sa = 0.f, sb = 0.f;
            #pragma unroll
            for (int q = 0; q < 4; ++q) { sa = fdot2f(pr[2*q], ones, sa); sb = fdot2f(pr[2*q+1], ones, sb); }
            l_own += sa + sb;
        }
    }

    l_own += __shfl_xor(l_own, 32);
    if (lane < 32) linv[mA + lane] = l_own;      // raw l
    __syncthreads();
    if (tid < 128) {
        const float inv = 1.0f / (linv[tid] + pz);
        linv[tid] = inv;
        pzn[tid]  = pz * inv;
    }
    __syncthreads();

    // epilogue: O = C*linv[row] + pzn[row]*bkv_v[col], f16 store
    #define EPI_TILE(CC, MI, NI) { \
        const int ch = (NI) * 16 + lr; \
        const float bv = bkv[128 + cb + ch]; \
        _Pragma("unroll") \
        for (int e = 0; e < 4; ++e) { \
            const int row = mA + (MI) * 16 + lg * 4 + e; \
            const float oo = fmaf(pzn[row], bv, CC[e] * linv[row]); \
            const int v2 = row >> 6, tt2 = (row >> 4) & 3, nn2 = (row >> 2) & 3, dd2 = row & 3; \
            const size_t tk = ((size_t)(v2 * 8 + t * 4 + tt2) * 1024 + n * 4 + nn2) * 4 + dd2; \
            o_out[tk * 128 + cb + ch] = (f16)oo; \
        } }
    EPI_TILE(oc00, 0, 0)
    EPI_TILE(oc01, 0, 1)
    EPI_TILE(oc10, 1, 0)
    EPI_TILE(oc11, 1, 1)
    #undef EPI_TILE
}

// ---------------- Kernel 2: row-local epilogue, 32 tokens/block x 8 threads/token ----------
__global__ __launch_bounds__(256, 3) void k_epi(
    const float* __restrict__ x, const f16* __restrict__ o_in,
    const float* __restrict__ bo, const float* __restrict__ gamma,
    const float* __restrict__ ln2_s, const float* __restrict__ ln2_b,
    const float* __restrict__ b1, const float* __restrict__ b2,
    const float* __restrict__ gm, float* __restrict__ out)
{
    constexpr int OLS = 132, H2S = 68, REDS = 17;
    __shared__ __align__(16) char smem[32 * OLS * 2 + 32 * H2S * 2 + 32 * REDS * 4]; // 14976 B
    f16* ol   = (f16*)smem;
    f16* h2l  = (f16*)(smem + 32 * OLS * 2);
    float* red = (float*)(smem + 32 * OLS * 2 + 32 * H2S * 2);
    f16* hidl = ol;

    const f16x2* WoP = g_wpack + OFF_WO;
    const f16x2* W1P = g_wpack + OFF_W1;
    const f16x2* W2P = g_wpack + OFF_W2;

    const int tid = threadIdx.x;
    const int r = tid & 31, s = tid >> 5;
    const int f0 = s * 8;
    const size_t tok = (size_t)blockIdx.x * 32 + r;

    {
        const f16x4* src = (const f16x4*)(o_in + tok * 128 + s * 16);
        f16x4* dst = (f16x4*)(ol + r * OLS + s * 16);
        #pragma unroll
        for (int m = 0; m < 4; ++m) dst[m] = src[m];
    }
    __syncthreads();

    float upd[8];
    #pragma unroll
    for (int j = 0; j < 8; ++j) upd[j] = bo[f0 + j];
    {
        const f16x4* orow = (const f16x4*)(ol + r * OLS);
        #pragma unroll 8
        for (int m = 0; m < 32; ++m) {
            const f16x4 c4 = orow[m];
            const f16x2 p0 = (f16x2){c4.x, c4.y}, p1 = (f16x2){c4.z, c4.w};
            #pragma unroll
            for (int j = 0; j < 8; ++j)
                upd[j] = fdot2f(p1, WoP[(f0+j)*64 + 2*m + 1], fdot2f(p0, WoP[(f0+j)*64 + 2*m], upd[j]));
        }
    }

    float tv[8]; float s1 = 0.f, s2 = 0.f;
    {
        const float* xr = x + tok * 64 + f0;
        #pragma unroll
        for (int j = 0; j < 8; ++j) {
            const float tk = xr[j] + gamma[f0 + j] * upd[j];
            tv[j] = tk; s1 += tk; s2 += tk * tk;
        }
    }
    red[r * REDS + s * 2]     = s1;
    red[r * REDS + s * 2 + 1] = s2;
    __syncthreads();
    {
        float a1 = 0.f, a2 = 0.f;
        #pragma unroll
        for (int i = 0; i < 8; ++i) { a1 += red[r*REDS + 2*i]; a2 += red[r*REDS + 2*i + 1]; }
        const float mean = a1 * 0.015625f;
        const float var  = a2 * 0.015625f - mean * mean;
        const float rstd = rsqrtf(var + 1e-5f);
        #pragma unroll
        for (int j = 0; j < 8; ++j)
            h2l[r * H2S + f0 + j] = (f16)((tv[j] - mean) * rstd * ln2_s[f0 + j] + ln2_b[f0 + j]);
    }
    __syncthreads();
    {
        const int a0 = s * 16;
        float ha[16];
        #pragma unroll
        for (int j = 0; j < 16; ++j) ha[j] = b1[a0 + j];
        const f16x4* h2row = (const f16x4*)(h2l + r * H2S);
        #pragma unroll 8
        for (int m = 0; m < 16; ++m) {
            const f16x4 c4 = h2row[m];
            const f16x2 p0 = (f16x2){c4.x, c4.y}, p1 = (f16x2){c4.z, c4.w};
            #pragma unroll
            for (int j = 0; j < 16; ++j)
                ha[j] = fdot2f(p1, W1P[(a0+j)*32 + 2*m + 1], fdot2f(p0, W1P[(a0+j)*32 + 2*m], ha[j]));
        }
        #pragma unroll
        for (int j = 0; j < 16; ++j) {
            const float z = ha[j];
            const float u = 0.7978845608028654f * (z + 0.044715f * z * z * z);
            hidl[r * OLS + a0 + j] = (f16)(0.5f * z * (1.0f + tanhf(u)));
        }
    }
    __syncthreads();
    {
        float oa[8];
        #pragma unroll
        for (int j = 0; j < 8; ++j) oa[j] = b2[f0 + j];
        const f16x4* hrow = (const f16x4*)(hidl + r * OLS);
        #pragma unroll 8
        for (int m = 0; m < 32; ++m) {
            const f16x4 c4 = hrow[m];
            const f16x2 p0 = (f16x2){c4.x, c4.y}, p1 = (f16x2){c4.z, c4.w};
            #pragma unroll
            for (int j = 0; j < 8; ++j)
                oa[j] = fdot2f(p1, W2P[(f0+j)*64 + 2*m + 1], fdot2f(p0, W2P[(f0+j)*64 + 2*m], oa[j]));
        }
        float* orow = out + tok * 64 + f0;
        #pragma unroll
        for (int j = 0; j < 8; ++j) orow[j] = tv[j] + gm[f0 + j] * oa[j];
    }
}

extern "C" void kernel_launch(void* const* d_in, const int* in_sizes, int n_in,
                              void* d_out, int out_size, void* d_ws, size_t ws_size,
                              hipStream_t stream) {
    const float* x        = (const float*)d_in[0];
    const float* ln1_s    = (const float*)d_in[1];
    const float* ln1_b    = (const float*)d_in[2];
    const float* Wq       = (const float*)d_in[3];
    const float* Wkv      = (const float*)d_in[4];
    const float* bkv      = (const float*)d_in[5];
    const float* Wo       = (const float*)d_in[6];
    const float* bo       = (const float*)d_in[7];
    const float* gamma    = (const float*)d_in[8];
    const float* ln2_s    = (const float*)d_in[9];
    const float* ln2_b    = (const float*)d_in[10];
    const float* W1       = (const float*)d_in[11];
    const float* b1       = (const float*)d_in[12];
    const float* W2       = (const float*)d_in[13];
    const float* b2       = (const float*)d_in[14];
    const float* gamma_mlp= (const float*)d_in[15];

    // o (f16[65536][128]) aliases d_out (f32[65536][64]); disjoint token partition
    // between k_att writes and k_epi reads/overwrites -> race-free.
    f16* o_buf = (f16*)d_out;
    float* out = (float*)d_out;

    hipLaunchKernelGGL(k_conv, dim3(NPAIRS / 256), dim3(256), 0, stream,
                       Wq, Wkv, Wo, W1, W2);
    hipLaunchKernelGGL(k_att, dim3(2048), dim3(256), 0, stream,
                       x, ln1_s, ln1_b, bkv, o_buf);
    hipLaunchKernelGGL(k_epi, dim3(2048), dim3(256), 0, stream,
                       x, o_buf, bo, gamma, ln2_s, ln2_b, b1, b2, gamma_mlp, out);
}

// Round 15
// 163.138 us; speedup vs baseline: 1.7302x; 1.7302x over previous
//
#include <hip/hip_runtime.h>
#include <math.h>

typedef _Float16 f16;
typedef _Float16 f16x2 __attribute__((ext_vector_type(2)));
typedef _Float16 f16x4 __attribute__((ext_vector_type(4)));
typedef _Float16 f16x8 __attribute__((ext_vector_type(8)));
typedef float f32x4 __attribute__((ext_vector_type(4)));

#if defined(__has_builtin)
#if __has_builtin(__builtin_amdgcn_fdot2)
#define USE_FDOT2 1
#endif
#if __has_builtin(__builtin_amdgcn_exp2f)
#define USE_EXP2 1
#endif
#endif

__device__ __forceinline__ float fdot2f(f16x2 a, f16x2 b, float c) {
#ifdef USE_FDOT2
    return __builtin_amdgcn_fdot2(a, b, c, false);
#else
    return c + (float)a.x * (float)b.x + (float)a.y * (float)b.y;
#endif
}
__device__ __forceinline__ float exp2fast(float a) {
#ifdef USE_EXP2
    return __builtin_amdgcn_exp2f(a);
#else
    return exp2f(a);
#endif
}

namespace {
// 192 real kv rows; 320 zero rows folded analytically (pz, multiplicity 320).
constexpr int NKV = 192;
constexpr int XLS = 65;    // f32/row x-stage stride (conflict-free)
constexpr int HLS = 72;    // f16/row LN'd h rows (144B, 16B-aligned)
constexpr int KS  = 40;    // f16/row k LDS
constexpr int QLS = 40;    // f16/row q LDS
constexpr int VTS = 200;   // f16/row V-transposed [32 ch][192 kv + pad]
constexpr int PSW = 40;    // f16/row per-wave P chunk [32][40]
// Timeline: xl f32[192][65]=49920 @0  ->  hl f16[192][72]=27648 @0
//   -> kl/vt/ql @27648..66048 (coexist with hl)  ->  Pw/li/pz overlay hl.
constexpr int OFF_HL = 0;
constexpr int OFF_KL = 27648;        // 15360 -> 43008
constexpr int OFF_VT = 43008;        // 12800 -> 55808
constexpr int OFF_QL = 55808;        // 10240 -> 66048
constexpr int OFF_PW = 0;            // 4*32*40*2 = 10240 (overlays dead hl)
constexpr int OFF_LI = 10240;        // f32[128]
constexpr int OFF_PZ = 10752;        // f32[128]
constexpr int ATT_LDS = 66048;       // >= xl 49920; -> 2 blocks/CU
constexpr float C1  = 0.2550600f;    // (1/sqrt(32)) * log2(e)
constexpr float CZN = -5.7707801f;   // -4*log2(e)  (fixed softmax shift; scores tiny)
constexpr float CZV = 2.5511480f;    // CZN + log2(320)

// packed-f16 weights: P[out][in/2] f16x2 pairs (row o = 64 contiguous f16 = W[:,o])
// => row o IS the MFMA B-fragment row for output-channel o.
constexpr int OFF_WQ  = 0;
constexpr int OFF_WKV = 4096;
constexpr int OFF_WO  = 12288;
constexpr int OFF_W1  = 16384;
constexpr int OFF_W2  = 20480;
constexpr int NPAIRS  = 24576;
}

__device__ f16x2 g_wpack[NPAIRS];

// ---------------- Kernel 0: pack GEMV weights to f16x2 ----------------
__global__ void k_conv(const float* __restrict__ Wq, const float* __restrict__ Wkv,
                       const float* __restrict__ Wo, const float* __restrict__ W1,
                       const float* __restrict__ W2) {
    const int i = blockIdx.x * 256 + threadIdx.x;
    const float* src; int inp, out, base;
    if (i < OFF_WKV)     { src = Wq;  inp = 32; out = 128; base = OFF_WQ;  }
    else if (i < OFF_WO) { src = Wkv; inp = 32; out = 256; base = OFF_WKV; }
    else if (i < OFF_W1) { src = Wo;  inp = 64; out = 64;  base = OFF_WO;  }
    else if (i < OFF_W2) { src = W1;  inp = 32; out = 128; base = OFF_W1;  }
    else                 { src = W2;  inp = 64; out = 64;  base = OFF_W2;  }
    const int li = i - base;
    const int o = li / inp, p = li % inp;
    g_wpack[i] = (f16x2){(f16)src[(2*p) * out + o], (f16)src[(2*p+1) * out + o]};
}

// ---------------- Kernel 1: per-(window,head) attention, all-MFMA ----------------
__global__ __launch_bounds__(256, 2) void k_att(
    const float* __restrict__ x,
    const float* __restrict__ ln1_s, const float* __restrict__ ln1_b,
    const float* __restrict__ bkv,
    f16* __restrict__ o_out)
{
    __shared__ __align__(16) char smem[ATT_LDS];
    float* xl = (float*)smem;                 // Phase A
    f16* hl   = (f16*)(smem + OFF_HL);        // Phase B2/C
    f16* kl   = (f16*)(smem + OFF_KL);
    f16* vt   = (f16*)(smem + OFF_VT);
    f16* ql   = (f16*)(smem + OFF_QL);
    float* linv = (float*)(smem + OFF_LI);
    float* pzn  = (float*)(smem + OFF_PZ);

    const int tid  = threadIdx.x;
    const int bid  = blockIdx.x;
    const int w    = bid & 511;
    const int head = bid >> 9;
    const int cb   = head * 32;
    const int n    = w & 255;
    const int t    = w >> 8;

    const int lane = tid & 63, wv = tid >> 6;
    const int lr = lane & 15, lg = lane >> 4;

    const f16* WqF  = (const f16*)(g_wpack + OFF_WQ);
    const f16* WkvF = (const f16*)(g_wpack + OFF_WKV);

    // ---- Phase A: cooperative coalesced x -> LDS (12 contiguous 4KB segments)
    #pragma unroll
    for (int s12 = 0; s12 < 12; ++s12) {
        const int v_ = s12 / 6;
        const int t2 = (s12 % 6) + ((t == 0) ? 2 : 0);
        int tsrc, tt;
        if (t2 < 2)      { tsrc = t - 1; tt = t2 + 2; }
        else if (t2 < 6) { tsrc = t;     tt = t2 - 2; }
        else             { tsrc = t + 1; tt = t2 - 6; }
        const size_t fbase = ((size_t)(v_ * 8 + tsrc * 4 + tt) * 1024 + n * 4) * 256;
        const float4 val = *(const float4*)(x + fbase + tid * 4);
        float* dst = xl + (s12 * 16 + (tid >> 4)) * XLS + (tid & 15) * 4;
        dst[0] = val.x; dst[1] = val.y; dst[2] = val.z; dst[3] = val.w;
    }
    __syncthreads();

    // ---- Phase B: LN from LDS into registers (threads 0-191, one kv row each)
    f16x2 h2[32];
    if (tid < NKV) {
        const float* xr = xl + tid * XLS;
        float s = 0.f, ss = 0.f;
        #pragma unroll
        for (int i = 0; i < 32; ++i) {
            const float a = xr[2*i], b = xr[2*i+1];
            s += a + b; ss += a*a + b*b;
            h2[i] = (f16x2){(f16)a, (f16)b};
        }
        const float mean = s * 0.015625f;
        const float rstd = rsqrtf(ss * 0.015625f - mean*mean + 1e-5f);
        #pragma unroll
        for (int i = 0; i < 32; ++i) {
            const float a0 = ((float)h2[i].x - mean) * rstd * ln1_s[2*i]   + ln1_b[2*i];
            const float a1 = ((float)h2[i].y - mean) * rstd * ln1_s[2*i+1] + ln1_b[2*i+1];
            h2[i] = (f16x2){(f16)a0, (f16)a1};
        }
    }
    __syncthreads();   // all xl reads done; hl overlays xl

    // ---- Phase B2: write h rows to hl
    if (tid < NKV) {
        f16* hr = hl + tid * HLS;
        #pragma unroll
        for (int m = 0; m < 8; ++m) {
            f16x8 p;
            #pragma unroll
            for (int j = 0; j < 4; ++j) { p[2*j] = h2[4*m+j].x; p[2*j+1] = h2[4*m+j].y; }
            ((f16x8*)(hr + m * 8))[0] = p;
        }
    }
    __syncthreads();   // hl ready

    // ---- Phase C: MFMA projections (r14 fix: per-thread GEMV chains -> matrix core).
    // Mapping validated by r12's QK/PV: A[m=lr][k=lg*8+j], B[n=lr][k], C[m=lg*4+e][n=lr].
    {
        // K and V: 12 m-tiles over 192 kv rows; wave wv owns 3.
        #pragma unroll
        for (int mi = 0; mi < 3; ++mi) {
            const int mb = (wv * 3 + mi) * 16;
            #pragma unroll
            for (int nt = 0; nt < 2; ++nt) {
                f32x4 ck = {0.f,0.f,0.f,0.f}, cv = {0.f,0.f,0.f,0.f};
                #pragma unroll
                for (int ks = 0; ks < 2; ++ks) {
                    const f16x8 af = *(const f16x8*)(hl + (mb + lr) * HLS + ks*32 + lg*8);
                    const f16x8 bk = *(const f16x8*)(WkvF + (cb + nt*16 + lr)*64 + ks*32 + lg*8);
                    const f16x8 bv = *(const f16x8*)(WkvF + (128 + cb + nt*16 + lr)*64 + ks*32 + lg*8);
                    ck = __builtin_amdgcn_mfma_f32_16x16x32_f16(af, bk, ck, 0, 0, 0);
                    cv = __builtin_amdgcn_mfma_f32_16x16x32_f16(af, bv, cv, 0, 0, 0);
                }
                const float bk_b = bkv[cb + nt*16 + lr];
                const float bv_b = bkv[128 + cb + nt*16 + lr];
                #pragma unroll
                for (int e = 0; e < 4; ++e) {
                    const int row = mb + lg*4 + e;
                    kl[row * KS + nt*16 + lr] = (f16)(ck[e] + bk_b);
                    vt[(nt*16 + lr) * VTS + row] = (f16)(cv[e] + bv_b);
                }
            }
        }
        // Q: 8 m-tiles over the 128 own-window rows; wave wv owns 2.
        #pragma unroll
        for (int mi = 0; mi < 2; ++mi) {
            const int qm = wv * 2 + mi;              // 0..7
            const int v_ = qm >> 2;
            const int hb = v_ * 96 + ((t == 0) ? 0 : 32) + (qm & 3) * 16;  // hl row base
            const int qb = v_ * 64 + (qm & 3) * 16;                         // ql row base
            #pragma unroll
            for (int nt = 0; nt < 2; ++nt) {
                f32x4 cq = {0.f,0.f,0.f,0.f};
                #pragma unroll
                for (int ks = 0; ks < 2; ++ks) {
                    const f16x8 af = *(const f16x8*)(hl + (hb + lr) * HLS + ks*32 + lg*8);
                    const f16x8 bq = *(const f16x8*)(WqF + (cb + nt*16 + lr)*64 + ks*32 + lg*8);
                    cq = __builtin_amdgcn_mfma_f32_16x16x32_f16(af, bq, cq, 0, 0, 0);
                }
                #pragma unroll
                for (int e = 0; e < 4; ++e)
                    ql[(qb + lg*4 + e) * QLS + nt*16 + lr] = (f16)cq[e];
            }
        }
    }
    __syncthreads();   // kl/vt/ql ready; hl dead (Pw may overlay)

    const int mA = wv * 32;                       // this wave's 32 output rows
    f16* Pw = (f16*)(smem + OFF_PW) + wv * 32 * PSW;

    // per-row virtual zero-token weight (threads 0-127, one per q row)
    float pz = 0.f;
    if (tid < 128) {
        const f16x2* qr2 = (const f16x2*)(ql + tid * QLS);
        float sz = 0.f;
        #pragma unroll
        for (int j = 0; j < 16; ++j)
            sz += (float)qr2[j].x * bkv[cb + 2*j] + (float)qr2[j].y * bkv[cb + 2*j + 1];
        pz = exp2fast(fmaf(sz, C1, CZV));
    }

    f32x4 oc00 = {0.f,0.f,0.f,0.f}, oc01 = {0.f,0.f,0.f,0.f};
    f32x4 oc10 = {0.f,0.f,0.f,0.f}, oc11 = {0.f,0.f,0.f,0.f};
    float l_own = 0.f;
    const int prow = lane & 31, pcolh = lane >> 5;

    // ---- flash: 6 chunks of 32 kv; per-wave P chunk -> no block barriers inside
    #pragma unroll 1
    for (int kk = 0; kk < 6; ++kk) {
        #pragma unroll
        for (int mi = 0; mi < 2; ++mi) {
            const f16x8 af = *(const f16x8*)(ql + (mA + mi*16 + lr) * QLS + lg * 8);
            #pragma unroll
            for (int nt = 0; nt < 2; ++nt) {
                const f16x8 bf = *(const f16x8*)(kl + (kk*32 + nt*16 + lr) * KS + lg * 8);
                const f32x4 c = __builtin_amdgcn_mfma_f32_16x16x32_f16(af, bf, (f32x4){0.f,0.f,0.f,0.f}, 0, 0, 0);
                #pragma unroll
                for (int e = 0; e < 4; ++e)
                    Pw[(mi*16 + lg*4 + e) * PSW + nt*16 + lr] = (f16)exp2fast(fmaf(c[e], C1, CZN));
            }
        }
        const f16x8 a0 = *(const f16x8*)(Pw + lr * PSW + lg * 8);
        const f16x8 a1 = *(const f16x8*)(Pw + (16 + lr) * PSW + lg * 8);
        const f16x8 b0 = *(const f16x8*)(vt + lr * VTS + kk*32 + lg*8);
        const f16x8 b1 = *(const f16x8*)(vt + (16 + lr) * VTS + kk*32 + lg*8);
        oc00 = __builtin_amdgcn_mfma_f32_16x16x32_f16(a0, b0, oc00, 0, 0, 0);
        oc01 = __builtin_amdgcn_mfma_f32_16x16x32_f16(a0, b1, oc01, 0, 0, 0);
        oc10 = __builtin_amdgcn_mfma_f32_16x16x32_f16(a1, b0, oc10, 0, 0, 0);
        oc11 = __builtin_amdgcn_mfma_f32_16x16x32_f16(a1, b1, oc11, 0, 0, 0);
        {
            const f16x2* pr = (const f16x2*)(Pw + prow * PSW + pcolh * 16);
            const f16x2 ones = (f16x2){(f16)1.f, (f16)1.f};
            float sa = 0.f, sb = 0.f;
            #pragma unroll
            for (int q = 0; q < 4; ++q) { sa = fdot2f(pr[2*q], ones, sa); sb = fdot2f(pr[2*q+1], ones, sb); }
            l_own += sa + sb;
        }
    }

    l_own += __shfl_xor(l_own, 32);
    if (lane < 32) linv[mA + lane] = l_own;      // raw l
    __syncthreads();
    if (tid < 128) {
        const float inv = 1.0f / (linv[tid] + pz);
        linv[tid] = inv;
        pzn[tid]  = pz * inv;
    }
    __syncthreads();

    // epilogue: O = C*linv[row] + pzn[row]*bkv_v[col], f16 store
    #define EPI_TILE(CC, MI, NI) { \
        const int ch = (NI) * 16 + lr; \
        const float bv = bkv[128 + cb + ch]; \
        _Pragma("unroll") \
        for (int e = 0; e < 4; ++e) { \
            const int row = mA + (MI) * 16 + lg * 4 + e; \
            const float oo = fmaf(pzn[row], bv, CC[e] * linv[row]); \
            const int v2 = row >> 6, tt2 = (row >> 4) & 3, nn2 = (row >> 2) & 3, dd2 = row & 3; \
            const size_t tk = ((size_t)(v2 * 8 + t * 4 + tt2) * 1024 + n * 4 + nn2) * 4 + dd2; \
            o_out[tk * 128 + cb + ch] = (f16)oo; \
        } }
    EPI_TILE(oc00, 0, 0)
    EPI_TILE(oc01, 0, 1)
    EPI_TILE(oc10, 1, 0)
    EPI_TILE(oc11, 1, 1)
    #undef EPI_TILE
}

// ---------------- Kernel 2: row-local epilogue, 32 tokens/block x 8 threads/token ----------
__global__ __launch_bounds__(256, 3) void k_epi(
    const float* __restrict__ x, const f16* __restrict__ o_in,
    const float* __restrict__ bo, const float* __restrict__ gamma,
    const float* __restrict__ ln2_s, const float* __restrict__ ln2_b,
    const float* __restrict__ b1, const float* __restrict__ b2,
    const float* __restrict__ gm, float* __restrict__ out)
{
    constexpr int OLS = 132, H2S = 68, REDS = 17;
    __shared__ __align__(16) char smem[32 * OLS * 2 + 32 * H2S * 2 + 32 * REDS * 4]; // 14976 B
    f16* ol   = (f16*)smem;
    f16* h2l  = (f16*)(smem + 32 * OLS * 2);
    float* red = (float*)(smem + 32 * OLS * 2 + 32 * H2S * 2);
    f16* hidl = ol;

    const f16x2* WoP = g_wpack + OFF_WO;
    const f16x2* W1P = g_wpack + OFF_W1;
    const f16x2* W2P = g_wpack + OFF_W2;

    const int tid = threadIdx.x;
    const int r = tid & 31, s = tid >> 5;
    const int f0 = s * 8;
    const size_t tok = (size_t)blockIdx.x * 32 + r;

    {
        const f16x4* src = (const f16x4*)(o_in + tok * 128 + s * 16);
        f16x4* dst = (f16x4*)(ol + r * OLS + s * 16);
        #pragma unroll
        for (int m = 0; m < 4; ++m) dst[m] = src[m];
    }
    __syncthreads();

    float upd[8];
    #pragma unroll
    for (int j = 0; j < 8; ++j) upd[j] = bo[f0 + j];
    {
        const f16x4* orow = (const f16x4*)(ol + r * OLS);
        #pragma unroll 8
        for (int m = 0; m < 32; ++m) {
            const f16x4 c4 = orow[m];
            const f16x2 p0 = (f16x2){c4.x, c4.y}, p1 = (f16x2){c4.z, c4.w};
            #pragma unroll
            for (int j = 0; j < 8; ++j)
                upd[j] = fdot2f(p1, WoP[(f0+j)*64 + 2*m + 1], fdot2f(p0, WoP[(f0+j)*64 + 2*m], upd[j]));
        }
    }

    float tv[8]; float s1 = 0.f, s2 = 0.f;
    {
        const float* xr = x + tok * 64 + f0;
        #pragma unroll
        for (int j = 0; j < 8; ++j) {
            const float tk = xr[j] + gamma[f0 + j] * upd[j];
            tv[j] = tk; s1 += tk; s2 += tk * tk;
        }
    }
    red[r * REDS + s * 2]     = s1;
    red[r * REDS + s * 2 + 1] = s2;
    __syncthreads();
    {
        float a1 = 0.f, a2 = 0.f;
        #pragma unroll
        for (int i = 0; i < 8; ++i) { a1 += red[r*REDS + 2*i]; a2 += red[r*REDS + 2*i + 1]; }
        const float mean = a1 * 0.015625f;
        const float var  = a2 * 0.015625f - mean * mean;
        const float rstd = rsqrtf(var + 1e-5f);
        #pragma unroll
        for (int j = 0; j < 8; ++j)
            h2l[r * H2S + f0 + j] = (f16)((tv[j] - mean) * rstd * ln2_s[f0 + j] + ln2_b[f0 + j]);
    }
    __syncthreads();
    {
        const int a0 = s * 16;
        float ha[16];
        #pragma unroll
        for (int j = 0; j < 16; ++j) ha[j] = b1[a0 + j];
        const f16x4* h2row = (const f16x4*)(h2l + r * H2S);
        #pragma unroll 8
        for (int m = 0; m < 16; ++m) {
            const f16x4 c4 = h2row[m];
            const f16x2 p0 = (f16x2){c4.x, c4.y}, p1 = (f16x2){c4.z, c4.w};
            #pragma unroll
            for (int j = 0; j < 16; ++j)
                ha[j] = fdot2f(p1, W1P[(a0+j)*32 + 2*m + 1], fdot2f(p0, W1P[(a0+j)*32 + 2*m], ha[j]));
        }
        #pragma unroll
        for (int j = 0; j < 16; ++j) {
            const float z = ha[j];
            const float u = 0.7978845608028654f * (z + 0.044715f * z * z * z);
            hidl[r * OLS + a0 + j] = (f16)(0.5f * z * (1.0f + tanhf(u)));
        }
    }
    __syncthreads();
    {
        float oa[8];
        #pragma unroll
        for (int j = 0; j < 8; ++j) oa[j] = b2[f0 + j];
        const f16x4* hrow = (const f16x4*)(hidl + r * OLS);
        #pragma unroll 8
        for (int m = 0; m < 32; ++m) {
            const f16x4 c4 = hrow[m];
            const f16x2 p0 = (f16x2){c4.x, c4.y}, p1 = (f16x2){c4.z, c4.w};
            #pragma unroll
            for (int j = 0; j < 8; ++j)
                oa[j] = fdot2f(p1, W2P[(f0+j)*64 + 2*m + 1], fdot2f(p0, W2P[(f0+j)*64 + 2*m], oa[j]));
        }
        float* orow = out + tok * 64 + f0;
        #pragma unroll
        for (int j = 0; j < 8; ++j) orow[j] = tv[j] + gm[f0 + j] * oa[j];
    }
}

extern "C" void kernel_launch(void* const* d_in, const int* in_sizes, int n_in,
                              void* d_out, int out_size, void* d_ws, size_t ws_size,
                              hipStream_t stream) {
    const float* x        = (const float*)d_in[0];
    const float* ln1_s    = (const float*)d_in[1];
    const float* ln1_b    = (const float*)d_in[2];
    const float* Wq       = (const float*)d_in[3];
    const float* Wkv      = (const float*)d_in[4];
    const float* bkv      = (const float*)d_in[5];
    const float* Wo       = (const float*)d_in[6];
    const float* bo       = (const float*)d_in[7];
    const float* gamma    = (const float*)d_in[8];
    const float* ln2_s    = (const float*)d_in[9];
    const float* ln2_b    = (const float*)d_in[10];
    const float* W1       = (const float*)d_in[11];
    const float* b1       = (const float*)d_in[12];
    const float* W2       = (const float*)d_in[13];
    const float* b2       = (const float*)d_in[14];
    const float* gamma_mlp= (const float*)d_in[15];

    // o (f16[65536][128]) aliases d_out (f32[65536][64]); disjoint token partition
    // between k_att writes and k_epi reads/overwrites -> race-free.
    f16* o_buf = (f16*)d_out;
    float* out = (float*)d_out;

    hipLaunchKernelGGL(k_conv, dim3(NPAIRS / 256), dim3(256), 0, stream,
                       Wq, Wkv, Wo, W1, W2);
    hipLaunchKernelGGL(k_att, dim3(2048), dim3(256), 0, stream,
                       x, ln1_s, ln1_b, bkv, o_buf);
    hipLaunchKernelGGL(k_epi, dim3(2048), dim3(256), 0, stream,
                       x, o_buf, bo, gamma, ln2_s, ln2_b, b1, b2, gamma_mlp, out);
}

// Round 17
// 97.272 us; speedup vs baseline: 2.9017x; 1.6771x over previous
//
#include <hip/hip_runtime.h>
#include <math.h>

typedef _Float16 f16;
typedef _Float16 f16x2 __attribute__((ext_vector_type(2)));
typedef _Float16 f16x4 __attribute__((ext_vector_type(4)));
typedef _Float16 f16x8 __attribute__((ext_vector_type(8)));
typedef float f32x4 __attribute__((ext_vector_type(4)));

#if defined(__has_builtin)
#if __has_builtin(__builtin_amdgcn_fdot2)
#define USE_FDOT2 1
#endif
#if __has_builtin(__builtin_amdgcn_exp2f)
#define USE_EXP2 1
#endif
#endif

__device__ __forceinline__ float fdot2f(f16x2 a, f16x2 b, float c) {
#ifdef USE_FDOT2
    return __builtin_amdgcn_fdot2(a, b, c, false);
#else
    return c + (float)a.x * (float)b.x + (float)a.y * (float)b.y;
#endif
}
__device__ __forceinline__ float exp2fast(float a) {
#ifdef USE_EXP2
    return __builtin_amdgcn_exp2f(a);
#else
    return exp2f(a);
#endif
}

namespace {
// ---- k_att constants (unchanged from r15) ----
constexpr int NKV = 192;
constexpr int XLS = 65;
constexpr int HLS = 72;
constexpr int KS  = 40;
constexpr int QLS = 40;
constexpr int VTS = 200;
constexpr int PSW = 40;
constexpr int OFF_HL = 0;
constexpr int OFF_KL = 27648;
constexpr int OFF_VT = 43008;
constexpr int OFF_QL = 55808;
constexpr int OFF_PW = 0;
constexpr int OFF_LI = 10240;
constexpr int OFF_PZ = 10752;
constexpr int ATT_LDS = 66048;
constexpr float C1  = 0.2550600f;
constexpr float CZN = -5.7707801f;
constexpr float CZV = 2.5511480f;

// ---- packed-f16 weights: P[out][in/2] f16x2 pairs; row o = W[:,o] = B-fragment row o
constexpr int OFF_WQ  = 0;
constexpr int OFF_WKV = 4096;
constexpr int OFF_WO  = 12288;
constexpr int OFF_W1  = 16384;
constexpr int OFF_W2  = 20480;
constexpr int NPAIRS  = 24576;

// ---- k_epi constants (MFMA epilogue, 64 tokens/block) ----
constexpr int EOLS = 136;   // f16/row o & hid (272B rows)
constexpr int ETVS = 66;    // f32/row tv
constexpr int EH2S = 72;    // f16/row h2
constexpr int OFF_EOL = 0;                   // 64*136*2 = 17408
constexpr int OFF_ETV = 17408;               // 64*66*4  = 16896 -> 34304
constexpr int OFF_EH2 = 34304;               // 64*72*2  = 9216  -> 43520
constexpr int OFF_ERD = 43520;               // 64*4*2 f32 = 2048 -> 45568
constexpr int EPI_LDS = 45568;               // x3 -> 3 blocks/CU
}

__device__ f16x2 g_wpack[NPAIRS];

// ---------------- Kernel 0: pack GEMV weights to f16x2 ----------------
__global__ void k_conv(const float* __restrict__ Wq, const float* __restrict__ Wkv,
                       const float* __restrict__ Wo, const float* __restrict__ W1,
                       const float* __restrict__ W2) {
    const int i = blockIdx.x * 256 + threadIdx.x;
    const float* src; int inp, out, base;
    if (i < OFF_WKV)     { src = Wq;  inp = 32; out = 128; base = OFF_WQ;  }
    else if (i < OFF_WO) { src = Wkv; inp = 32; out = 256; base = OFF_WKV; }
    else if (i < OFF_W1) { src = Wo;  inp = 64; out = 64;  base = OFF_WO;  }
    else if (i < OFF_W2) { src = W1;  inp = 32; out = 128; base = OFF_W1;  }
    else                 { src = W2;  inp = 64; out = 64;  base = OFF_W2;  }
    const int li = i - base;
    const int o = li / inp, p = li % inp;
    g_wpack[i] = (f16x2){(f16)src[(2*p) * out + o], (f16)src[(2*p+1) * out + o]};
}

// ---------------- Kernel 1: per-(window,head) attention, all-MFMA (r15, unchanged) ----------
__global__ __launch_bounds__(256, 2) void k_att(
    const float* __restrict__ x,
    const float* __restrict__ ln1_s, const float* __restrict__ ln1_b,
    const float* __restrict__ bkv,
    f16* __restrict__ o_out)
{
    __shared__ __align__(16) char smem[ATT_LDS];
    float* xl = (float*)smem;
    f16* hl   = (f16*)(smem + OFF_HL);
    f16* kl   = (f16*)(smem + OFF_KL);
    f16* vt   = (f16*)(smem + OFF_VT);
    f16* ql   = (f16*)(smem + OFF_QL);
    float* linv = (float*)(smem + OFF_LI);
    float* pzn  = (float*)(smem + OFF_PZ);

    const int tid  = threadIdx.x;
    const int bid  = blockIdx.x;
    const int w    = bid & 511;
    const int head = bid >> 9;
    const int cb   = head * 32;
    const int n    = w & 255;
    const int t    = w >> 8;

    const int lane = tid & 63, wv = tid >> 6;
    const int lr = lane & 15, lg = lane >> 4;

    const f16* WqF  = (const f16*)(g_wpack + OFF_WQ);
    const f16* WkvF = (const f16*)(g_wpack + OFF_WKV);

    // Phase A: cooperative coalesced x -> LDS (12 contiguous 4KB segments)
    #pragma unroll
    for (int s12 = 0; s12 < 12; ++s12) {
        const int v_ = s12 / 6;
        const int t2 = (s12 % 6) + ((t == 0) ? 2 : 0);
        int tsrc, tt;
        if (t2 < 2)      { tsrc = t - 1; tt = t2 + 2; }
        else if (t2 < 6) { tsrc = t;     tt = t2 - 2; }
        else             { tsrc = t + 1; tt = t2 - 6; }
        const size_t fbase = ((size_t)(v_ * 8 + tsrc * 4 + tt) * 1024 + n * 4) * 256;
        const float4 val = *(const float4*)(x + fbase + tid * 4);
        float* dst = xl + (s12 * 16 + (tid >> 4)) * XLS + (tid & 15) * 4;
        dst[0] = val.x; dst[1] = val.y; dst[2] = val.z; dst[3] = val.w;
    }
    __syncthreads();

    // Phase B: LN from LDS into registers (threads 0-191)
    f16x2 h2[32];
    if (tid < NKV) {
        const float* xr = xl + tid * XLS;
        float s = 0.f, ss = 0.f;
        #pragma unroll
        for (int i = 0; i < 32; ++i) {
            const float a = xr[2*i], b = xr[2*i+1];
            s += a + b; ss += a*a + b*b;
            h2[i] = (f16x2){(f16)a, (f16)b};
        }
        const float mean = s * 0.015625f;
        const float rstd = rsqrtf(ss * 0.015625f - mean*mean + 1e-5f);
        #pragma unroll
        for (int i = 0; i < 32; ++i) {
            const float a0 = ((float)h2[i].x - mean) * rstd * ln1_s[2*i]   + ln1_b[2*i];
            const float a1 = ((float)h2[i].y - mean) * rstd * ln1_s[2*i+1] + ln1_b[2*i+1];
            h2[i] = (f16x2){(f16)a0, (f16)a1};
        }
    }
    __syncthreads();

    // Phase B2: h rows -> hl
    if (tid < NKV) {
        f16* hr = hl + tid * HLS;
        #pragma unroll
        for (int m = 0; m < 8; ++m) {
            f16x8 p;
            #pragma unroll
            for (int j = 0; j < 4; ++j) { p[2*j] = h2[4*m+j].x; p[2*j+1] = h2[4*m+j].y; }
            ((f16x8*)(hr + m * 8))[0] = p;
        }
    }
    __syncthreads();

    // Phase C: MFMA projections
    {
        #pragma unroll
        for (int mi = 0; mi < 3; ++mi) {
            const int mb = (wv * 3 + mi) * 16;
            #pragma unroll
            for (int nt = 0; nt < 2; ++nt) {
                f32x4 ck = {0.f,0.f,0.f,0.f}, cv = {0.f,0.f,0.f,0.f};
                #pragma unroll
                for (int ks = 0; ks < 2; ++ks) {
                    const f16x8 af = *(const f16x8*)(hl + (mb + lr) * HLS + ks*32 + lg*8);
                    const f16x8 bk = *(const f16x8*)(WkvF + (cb + nt*16 + lr)*64 + ks*32 + lg*8);
                    const f16x8 bv = *(const f16x8*)(WkvF + (128 + cb + nt*16 + lr)*64 + ks*32 + lg*8);
                    ck = __builtin_amdgcn_mfma_f32_16x16x32_f16(af, bk, ck, 0, 0, 0);
                    cv = __builtin_amdgcn_mfma_f32_16x16x32_f16(af, bv, cv, 0, 0, 0);
                }
                const float bk_b = bkv[cb + nt*16 + lr];
                const float bv_b = bkv[128 + cb + nt*16 + lr];
                #pragma unroll
                for (int e = 0; e < 4; ++e) {
                    const int row = mb + lg*4 + e;
                    kl[row * KS + nt*16 + lr] = (f16)(ck[e] + bk_b);
                    vt[(nt*16 + lr) * VTS + row] = (f16)(cv[e] + bv_b);
                }
            }
        }
        #pragma unroll
        for (int mi = 0; mi < 2; ++mi) {
            const int qm = wv * 2 + mi;
            const int v_ = qm >> 2;
            const int hb = v_ * 96 + ((t == 0) ? 0 : 32) + (qm & 3) * 16;
            const int qb = v_ * 64 + (qm & 3) * 16;
            #pragma unroll
            for (int nt = 0; nt < 2; ++nt) {
                f32x4 cq = {0.f,0.f,0.f,0.f};
                #pragma unroll
                for (int ks = 0; ks < 2; ++ks) {
                    const f16x8 af = *(const f16x8*)(hl + (hb + lr) * HLS + ks*32 + lg*8);
                    const f16x8 bq = *(const f16x8*)(WqF + (cb + nt*16 + lr)*64 + ks*32 + lg*8);
                    cq = __builtin_amdgcn_mfma_f32_16x16x32_f16(af, bq, cq, 0, 0, 0);
                }
                #pragma unroll
                for (int e = 0; e < 4; ++e)
                    ql[(qb + lg*4 + e) * QLS + nt*16 + lr] = (f16)cq[e];
            }
        }
    }
    __syncthreads();

    const int mA = wv * 32;
    f16* Pw = (f16*)(smem + OFF_PW) + wv * 32 * PSW;

    float pz = 0.f;
    if (tid < 128) {
        const f16x2* qr2 = (const f16x2*)(ql + tid * QLS);
        float sz = 0.f;
        #pragma unroll
        for (int j = 0; j < 16; ++j)
            sz += (float)qr2[j].x * bkv[cb + 2*j] + (float)qr2[j].y * bkv[cb + 2*j + 1];
        pz = exp2fast(fmaf(sz, C1, CZV));
    }

    f32x4 oc00 = {0.f,0.f,0.f,0.f}, oc01 = {0.f,0.f,0.f,0.f};
    f32x4 oc10 = {0.f,0.f,0.f,0.f}, oc11 = {0.f,0.f,0.f,0.f};
    float l_own = 0.f;
    const int prow = lane & 31, pcolh = lane >> 5;

    #pragma unroll 1
    for (int kk = 0; kk < 6; ++kk) {
        #pragma unroll
        for (int mi = 0; mi < 2; ++mi) {
            const f16x8 af = *(const f16x8*)(ql + (mA + mi*16 + lr) * QLS + lg * 8);
            #pragma unroll
            for (int nt = 0; nt < 2; ++nt) {
                const f16x8 bf = *(const f16x8*)(kl + (kk*32 + nt*16 + lr) * KS + lg * 8);
                const f32x4 c = __builtin_amdgcn_mfma_f32_16x16x32_f16(af, bf, (f32x4){0.f,0.f,0.f,0.f}, 0, 0, 0);
                #pragma unroll
                for (int e = 0; e < 4; ++e)
                    Pw[(mi*16 + lg*4 + e) * PSW + nt*16 + lr] = (f16)exp2fast(fmaf(c[e], C1, CZN));
            }
        }
        const f16x8 a0 = *(const f16x8*)(Pw + lr * PSW + lg * 8);
        const f16x8 a1 = *(const f16x8*)(Pw + (16 + lr) * PSW + lg * 8);
        const f16x8 b0 = *(const f16x8*)(vt + lr * VTS + kk*32 + lg*8);
        const f16x8 b1 = *(const f16x8*)(vt + (16 + lr) * VTS + kk*32 + lg*8);
        oc00 = __builtin_amdgcn_mfma_f32_16x16x32_f16(a0, b0, oc00, 0, 0, 0);
        oc01 = __builtin_amdgcn_mfma_f32_16x16x32_f16(a0, b1, oc01, 0, 0, 0);
        oc10 = __builtin_amdgcn_mfma_f32_16x16x32_f16(a1, b0, oc10, 0, 0, 0);
        oc11 = __builtin_amdgcn_mfma_f32_16x16x32_f16(a1, b1, oc11, 0, 0, 0);
        {
            const f16x2* pr = (const f16x2*)(Pw + prow * PSW + pcolh * 16);
            const f16x2 ones = (f16x2){(f16)1.f, (f16)1.f};
            float sa = 0.f, sb = 0.f;
            #pragma unroll
            for (int q = 0; q < 4; ++q) { sa = fdot2f(pr[2*q], ones, sa); sb = fdot2f(pr[2*q+1], ones, sb); }
            l_own += sa + sb;
        }
    }

    l_own += __shfl_xor(l_own, 32);
    if (lane < 32) linv[mA + lane] = l_own;
    __syncthreads();
    if (tid < 128) {
        const float inv = 1.0f / (linv[tid] + pz);
        linv[tid] = inv;
        pzn[tid]  = pz * inv;
    }
    __syncthreads();

    #define EPI_TILE(CC, MI, NI) { \
        const int ch = (NI) * 16 + lr; \
        const float bv = bkv[128 + cb + ch]; \
        _Pragma("unroll") \
        for (int e = 0; e < 4; ++e) { \
            const int row = mA + (MI) * 16 + lg * 4 + e; \
            const float oo = fmaf(pzn[row], bv, CC[e] * linv[row]); \
            const int v2 = row >> 6, tt2 = (row >> 4) & 3, nn2 = (row >> 2) & 3, dd2 = row & 3; \
            const size_t tk = ((size_t)(v2 * 8 + t * 4 + tt2) * 1024 + n * 4 + nn2) * 4 + dd2; \
            o_out[tk * 128 + cb + ch] = (f16)oo; \
        } }
    EPI_TILE(oc00, 0, 0)
    EPI_TILE(oc01, 0, 1)
    EPI_TILE(oc10, 1, 0)
    EPI_TILE(oc11, 1, 1)
    #undef EPI_TILE
}

// ---------------- Kernel 2: MFMA epilogue, 64 tokens/block ----------------
// r16 NaN fix: Phase A now copies the FULL 32 f16 per thread (was 16 -> half of
// the o-tile uninitialized LDS -> NaN through the Wo MFMA).
__global__ __launch_bounds__(256, 3) void k_epi(
    const float* __restrict__ x, const f16* __restrict__ o_in,
    const float* __restrict__ bo, const float* __restrict__ gamma,
    const float* __restrict__ ln2_s, const float* __restrict__ ln2_b,
    const float* __restrict__ b1, const float* __restrict__ b2,
    const float* __restrict__ gm, float* __restrict__ out)
{
    __shared__ __align__(16) char smem[EPI_LDS];
    f16* eol    = (f16*)(smem + OFF_EOL);    // [64][136] o rows; hid overlays after LN2
    float* etv  = (float*)(smem + OFF_ETV);  // [64][66] tv f32
    f16* eh2    = (f16*)(smem + OFF_EH2);    // [64][72] LN2 output
    float* erd  = (float*)(smem + OFF_ERD);  // [64][4][2] LN2 partials
    f16* ehid   = eol;                       // overlay

    const f16* WoF = (const f16*)(g_wpack + OFF_WO);   // rows of 128 f16
    const f16* W1F = (const f16*)(g_wpack + OFF_W1);   // rows of 64 f16
    const f16* W2F = (const f16*)(g_wpack + OFF_W2);   // rows of 128 f16

    const int tid = threadIdx.x;
    const int lane = tid & 63, wv = tid >> 6;
    const int lr = lane & 15, lg = lane >> 4;
    const int mb = wv * 16;                       // this wave's 16 tokens
    const size_t tok0 = (size_t)blockIdx.x * 64;

    {   // Phase A: coalesced o -> LDS; 32 f16 (64B) per thread = full tile
        const int tk = tid >> 2, part = tid & 3;
        const f16x8* src = (const f16x8*)(o_in + (tok0 + tk) * 128 + part * 32);
        f16x8* dst = (f16x8*)(eol + tk * EOLS + part * 32);
        dst[0] = src[0]; dst[1] = src[1]; dst[2] = src[2]; dst[3] = src[3];
    }
    __syncthreads();

    {   // Phase B: upd = o @ Wo (MFMA, K=128); fused residual -> tv
        f16x8 a_[4];
        #pragma unroll
        for (int ks = 0; ks < 4; ++ks)
            a_[ks] = *(const f16x8*)(eol + (mb + lr) * EOLS + ks*32 + lg*8);
        #pragma unroll
        for (int nt = 0; nt < 4; ++nt) {
            const int ch = nt * 16 + lr;
            f32x4 c = {0.f,0.f,0.f,0.f};
            c = __builtin_amdgcn_mfma_f32_16x16x32_f16(a_[0], *(const f16x8*)(WoF + ch*128 +  0 + lg*8), c, 0, 0, 0);
            c = __builtin_amdgcn_mfma_f32_16x16x32_f16(a_[1], *(const f16x8*)(WoF + ch*128 + 32 + lg*8), c, 0, 0, 0);
            c = __builtin_amdgcn_mfma_f32_16x16x32_f16(a_[2], *(const f16x8*)(WoF + ch*128 + 64 + lg*8), c, 0, 0, 0);
            c = __builtin_amdgcn_mfma_f32_16x16x32_f16(a_[3], *(const f16x8*)(WoF + ch*128 + 96 + lg*8), c, 0, 0, 0);
            const float bo_c = bo[ch], ga_c = gamma[ch];
            #pragma unroll
            for (int e = 0; e < 4; ++e) {
                const int tk = mb + lg*4 + e;
                etv[tk * ETVS + ch] = x[(tok0 + tk)*64 + ch] + ga_c * (c[e] + bo_c);
            }
        }
    }
    __syncthreads();

    {   // Phase C1: LN2 partial stats (4 threads/token)
        const int tk = tid >> 2, q = tid & 3;
        const float* tr = etv + tk * ETVS + q * 16;
        float s1 = 0.f, s2 = 0.f;
        #pragma unroll
        for (int j = 0; j < 16; ++j) { const float v = tr[j]; s1 += v; s2 += v*v; }
        erd[(tk*4 + q)*2] = s1; erd[(tk*4 + q)*2 + 1] = s2;
    }
    __syncthreads();
    {   // Phase C2: finalize LN2 -> eh2 (f16)
        const int tk = tid >> 2, q = tid & 3;
        float a1 = 0.f, a2 = 0.f;
        #pragma unroll
        for (int i = 0; i < 4; ++i) { a1 += erd[(tk*4 + i)*2]; a2 += erd[(tk*4 + i)*2 + 1]; }
        const float mean = a1 * 0.015625f;
        const float rstd = rsqrtf(a2 * 0.015625f - mean*mean + 1e-5f);
        const float* tr = etv + tk * ETVS + q * 16;
        f16* hr = eh2 + tk * EH2S + q * 16;
        #pragma unroll
        for (int j = 0; j < 16; ++j)
            hr[j] = (f16)((tr[j]-mean)*rstd*ln2_s[q*16 + j] + ln2_b[q*16 + j]);
    }
    __syncthreads();

    {   // Phase D: hid = gelu(h2 @ W1) (MFMA, K=64); hid overlays dead o buffer.
        f16x8 a_[2];
        #pragma unroll
        for (int ks = 0; ks < 2; ++ks)
            a_[ks] = *(const f16x8*)(eh2 + (mb + lr) * EH2S + ks*32 + lg*8);
        #pragma unroll
        for (int nt = 0; nt < 8; ++nt) {
            const int ch = nt * 16 + lr;
            f32x4 c = {0.f,0.f,0.f,0.f};
            c = __builtin_amdgcn_mfma_f32_16x16x32_f16(a_[0], *(const f16x8*)(W1F + ch*64 +  0 + lg*8), c, 0, 0, 0);
            c = __builtin_amdgcn_mfma_f32_16x16x32_f16(a_[1], *(const f16x8*)(W1F + ch*64 + 32 + lg*8), c, 0, 0, 0);
            const float b1_c = b1[ch];
            #pragma unroll
            for (int e = 0; e < 4; ++e) {
                const int tk = mb + lg*4 + e;
                const float z = c[e] + b1_c;
                const float u = 0.7978845608028654f * (z + 0.044715f * z*z*z);
                ehid[tk * EOLS + ch] = (f16)(z / (1.0f + exp2fast(-2.8853900817779268f * u)));
            }
        }
    }
    __syncthreads();

    {   // Phase E: oa = hid @ W2 (MFMA, K=128); final residual -> out
        f16x8 a_[4];
        #pragma unroll
        for (int ks = 0; ks < 4; ++ks)
            a_[ks] = *(const f16x8*)(ehid + (mb + lr) * EOLS + ks*32 + lg*8);
        #pragma unroll
        for (int nt = 0; nt < 4; ++nt) {
            const int ch = nt * 16 + lr;
            f32x4 c = {0.f,0.f,0.f,0.f};
            c = __builtin_amdgcn_mfma_f32_16x16x32_f16(a_[0], *(const f16x8*)(W2F + ch*128 +  0 + lg*8), c, 0, 0, 0);
            c = __builtin_amdgcn_mfma_f32_16x16x32_f16(a_[1], *(const f16x8*)(W2F + ch*128 + 32 + lg*8), c, 0, 0, 0);
            c = __builtin_amdgcn_mfma_f32_16x16x32_f16(a_[2], *(const f16x8*)(W2F + ch*128 + 64 + lg*8), c, 0, 0, 0);
            c = __builtin_amdgcn_mfma_f32_16x16x32_f16(a_[3], *(const f16x8*)(W2F + ch*128 + 96 + lg*8), c, 0, 0, 0);
            const float b2_c = b2[ch], gm_c = gm[ch];
            #pragma unroll
            for (int e = 0; e < 4; ++e) {
                const int tk = mb + lg*4 + e;
                out[(tok0 + tk)*64 + ch] = etv[tk * ETVS + ch] + gm_c * (c[e] + b2_c);
            }
        }
    }
}

extern "C" void kernel_launch(void* const* d_in, const int* in_sizes, int n_in,
                              void* d_out, int out_size, void* d_ws, size_t ws_size,
                              hipStream_t stream) {
    const float* x        = (const float*)d_in[0];
    const float* ln1_s    = (const float*)d_in[1];
    const float* ln1_b    = (const float*)d_in[2];
    const float* Wq       = (const float*)d_in[3];
    const float* Wkv      = (const float*)d_in[4];
    const float* bkv      = (const float*)d_in[5];
    const float* Wo       = (const float*)d_in[6];
    const float* bo       = (const float*)d_in[7];
    const float* gamma    = (const float*)d_in[8];
    const float* ln2_s    = (const float*)d_in[9];
    const float* ln2_b    = (const float*)d_in[10];
    const float* W1       = (const float*)d_in[11];
    const float* b1       = (const float*)d_in[12];
    const float* W2       = (const float*)d_in[13];
    const float* b2       = (const float*)d_in[14];
    const float* gamma_mlp= (const float*)d_in[15];

    // o (f16[65536][128]) aliases d_out (f32[65536][64]); disjoint token partition
    // between k_att writes and k_epi reads/overwrites -> race-free.
    f16* o_buf = (f16*)d_out;
    float* out = (float*)d_out;

    hipLaunchKernelGGL(k_conv, dim3(NPAIRS / 256), dim3(256), 0, stream,
                       Wq, Wkv, Wo, W1, W2);
    hipLaunchKernelGGL(k_att, dim3(2048), dim3(256), 0, stream,
                       x, ln1_s, ln1_b, bkv, o_buf);
    hipLaunchKernelGGL(k_epi, dim3(1024), dim3(256), 0, stream,
                       x, o_buf, bo, gamma, ln2_s, ln2_b, b1, b2, gamma_mlp, out);
}

// Round 18
// 82.523 us; speedup vs baseline: 3.4203x; 1.1787x over previous
//
#include <hip/hip_runtime.h>
#include <math.h>

typedef _Float16 f16;
typedef _Float16 f16x2 __attribute__((ext_vector_type(2)));
typedef _Float16 f16x4 __attribute__((ext_vector_type(4)));
typedef _Float16 f16x8 __attribute__((ext_vector_type(8)));
typedef float f32x4 __attribute__((ext_vector_type(4)));

#if defined(__has_builtin)
#if __has_builtin(__builtin_amdgcn_fdot2)
#define USE_FDOT2 1
#endif
#if __has_builtin(__builtin_amdgcn_exp2f)
#define USE_EXP2 1
#endif
#endif

__device__ __forceinline__ float fdot2f(f16x2 a, f16x2 b, float c) {
#ifdef USE_FDOT2
    return __builtin_amdgcn_fdot2(a, b, c, false);
#else
    return c + (float)a.x * (float)b.x + (float)a.y * (float)b.y;
#endif
}
__device__ __forceinline__ float exp2fast(float a) {
#ifdef USE_EXP2
    return __builtin_amdgcn_exp2f(a);
#else
    return exp2f(a);
#endif
}

namespace {
// ---- k_att constants (r17: one block per WINDOW, 4-head loop) ----
constexpr int NKV = 192;
constexpr int XLS = 65;    // f32/row x-stage stride
constexpr int HLS = 72;    // f16/row LN'd h rows (persists across heads)
constexpr int KS  = 40;
constexpr int QLS = 40;
constexpr int VTS = 200;
constexpr int PSW = 40;
// Layout: xl f32[192][65]=49920 @0 (Phase A/B only), then:
constexpr int OFF_HL = 0;            // 27648 (overlays dead xl)
constexpr int OFF_KL = 27648;        // 15360 -> 43008
constexpr int OFF_VT = 43008;        // 12800 -> 55808
constexpr int OFF_QL = 55808;        // 10240 -> 66048
constexpr int OFF_PW = 66048;        // 10240 -> 76288 (hl persists; no overlay)
constexpr int OFF_LI = 76288;        // f32[128] -> 76800
constexpr int OFF_PZ = 76800;        // f32[128] -> 77312
constexpr int ATT_LDS = 77312;       // >= xl 49920; x2 = 154624 < 160K -> 2 blocks/CU
constexpr float C1  = 0.2550600f;
constexpr float CZN = -5.7707801f;
constexpr float CZV = 2.5511480f;

// ---- packed-f16 weights: P[out][in/2] f16x2 pairs; row o = W[:,o] = B-fragment row o
constexpr int OFF_WQ  = 0;
constexpr int OFF_WKV = 4096;
constexpr int OFF_WO  = 12288;
constexpr int OFF_W1  = 16384;
constexpr int OFF_W2  = 20480;
constexpr int NPAIRS  = 24576;

// ---- k_epi constants (unchanged from r17) ----
constexpr int EOLS = 136;
constexpr int ETVS = 66;
constexpr int EH2S = 72;
constexpr int OFF_EOL = 0;
constexpr int OFF_ETV = 17408;
constexpr int OFF_EH2 = 34304;
constexpr int OFF_ERD = 43520;
constexpr int EPI_LDS = 45568;
}

__device__ f16x2 g_wpack[NPAIRS];

// ---------------- Kernel 0: pack GEMV weights to f16x2 ----------------
__global__ void k_conv(const float* __restrict__ Wq, const float* __restrict__ Wkv,
                       const float* __restrict__ Wo, const float* __restrict__ W1,
                       const float* __restrict__ W2) {
    const int i = blockIdx.x * 256 + threadIdx.x;
    const float* src; int inp, out, base;
    if (i < OFF_WKV)     { src = Wq;  inp = 32; out = 128; base = OFF_WQ;  }
    else if (i < OFF_WO) { src = Wkv; inp = 32; out = 256; base = OFF_WKV; }
    else if (i < OFF_W1) { src = Wo;  inp = 64; out = 64;  base = OFF_WO;  }
    else if (i < OFF_W2) { src = W1;  inp = 32; out = 128; base = OFF_W1;  }
    else                 { src = W2;  inp = 64; out = 64;  base = OFF_W2;  }
    const int li = i - base;
    const int o = li / inp, p = li % inp;
    g_wpack[i] = (f16x2){(f16)src[(2*p) * out + o], (f16)src[(2*p+1) * out + o]};
}

// ---------------- Kernel 1: per-WINDOW attention, 4-head loop, all-MFMA ----------------
// r17: the 4 head-blocks each re-staged x and re-LN'd the same 192 rows (4x duplicate
// work chip-wide) and 2048 blocks ran in 4 sequential occupancy rounds. Now: 512
// blocks (1/window), stage+LN once, loop heads reusing kl/vt/ql/Pw.
__global__ __launch_bounds__(256, 2) void k_att(
    const float* __restrict__ x,
    const float* __restrict__ ln1_s, const float* __restrict__ ln1_b,
    const float* __restrict__ bkv,
    f16* __restrict__ o_out)
{
    __shared__ __align__(16) char smem[ATT_LDS];
    float* xl = (float*)smem;
    f16* hl   = (f16*)(smem + OFF_HL);
    f16* kl   = (f16*)(smem + OFF_KL);
    f16* vt   = (f16*)(smem + OFF_VT);
    f16* ql   = (f16*)(smem + OFF_QL);
    float* linv = (float*)(smem + OFF_LI);
    float* pzn  = (float*)(smem + OFF_PZ);

    const int tid  = threadIdx.x;
    const int w    = blockIdx.x;          // window 0..511
    const int n    = w & 255;
    const int t    = w >> 8;

    const int lane = tid & 63, wv = tid >> 6;
    const int lr = lane & 15, lg = lane >> 4;

    const f16* WqF  = (const f16*)(g_wpack + OFF_WQ);
    const f16* WkvF = (const f16*)(g_wpack + OFF_WKV);

    // Phase A: cooperative coalesced x -> LDS (12 contiguous 4KB segments)
    #pragma unroll
    for (int s12 = 0; s12 < 12; ++s12) {
        const int v_ = s12 / 6;
        const int t2 = (s12 % 6) + ((t == 0) ? 2 : 0);
        int tsrc, tt;
        if (t2 < 2)      { tsrc = t - 1; tt = t2 + 2; }
        else if (t2 < 6) { tsrc = t;     tt = t2 - 2; }
        else             { tsrc = t + 1; tt = t2 - 6; }
        const size_t fbase = ((size_t)(v_ * 8 + tsrc * 4 + tt) * 1024 + n * 4) * 256;
        const float4 val = *(const float4*)(x + fbase + tid * 4);
        float* dst = xl + (s12 * 16 + (tid >> 4)) * XLS + (tid & 15) * 4;
        dst[0] = val.x; dst[1] = val.y; dst[2] = val.z; dst[3] = val.w;
    }
    __syncthreads();

    // Phase B: LN from LDS into registers (threads 0-191)
    f16x2 h2[32];
    if (tid < NKV) {
        const float* xr = xl + tid * XLS;
        float s = 0.f, ss = 0.f;
        #pragma unroll
        for (int i = 0; i < 32; ++i) {
            const float a = xr[2*i], b = xr[2*i+1];
            s += a + b; ss += a*a + b*b;
            h2[i] = (f16x2){(f16)a, (f16)b};
        }
        const float mean = s * 0.015625f;
        const float rstd = rsqrtf(ss * 0.015625f - mean*mean + 1e-5f);
        #pragma unroll
        for (int i = 0; i < 32; ++i) {
            const float a0 = ((float)h2[i].x - mean) * rstd * ln1_s[2*i]   + ln1_b[2*i];
            const float a1 = ((float)h2[i].y - mean) * rstd * ln1_s[2*i+1] + ln1_b[2*i+1];
            h2[i] = (f16x2){(f16)a0, (f16)a1};
        }
    }
    __syncthreads();   // all xl reads done; hl overlays xl

    // Phase B2: h rows -> hl (persists across all 4 heads)
    if (tid < NKV) {
        f16* hr = hl + tid * HLS;
        #pragma unroll
        for (int m = 0; m < 8; ++m) {
            f16x8 p;
            #pragma unroll
            for (int j = 0; j < 4; ++j) { p[2*j] = h2[4*m+j].x; p[2*j+1] = h2[4*m+j].y; }
            ((f16x8*)(hr + m * 8))[0] = p;
        }
    }
    __syncthreads();   // hl ready

    const int mA = wv * 32;
    f16* Pw = (f16*)(smem + OFF_PW) + wv * 32 * PSW;
    const int prow = lane & 31, pcolh = lane >> 5;

    // ---- head loop: projections + flash + o write, reusing kl/vt/ql/Pw
    #pragma unroll 1
    for (int head = 0; head < 4; ++head) {
        const int cb = head * 32;

        // Phase C: MFMA projections for this head
        {
            #pragma unroll
            for (int mi = 0; mi < 3; ++mi) {
                const int mb = (wv * 3 + mi) * 16;
                #pragma unroll
                for (int nt = 0; nt < 2; ++nt) {
                    f32x4 ck = {0.f,0.f,0.f,0.f}, cv = {0.f,0.f,0.f,0.f};
                    #pragma unroll
                    for (int ks = 0; ks < 2; ++ks) {
                        const f16x8 af = *(const f16x8*)(hl + (mb + lr) * HLS + ks*32 + lg*8);
                        const f16x8 bk = *(const f16x8*)(WkvF + (cb + nt*16 + lr)*64 + ks*32 + lg*8);
                        const f16x8 bv = *(const f16x8*)(WkvF + (128 + cb + nt*16 + lr)*64 + ks*32 + lg*8);
                        ck = __builtin_amdgcn_mfma_f32_16x16x32_f16(af, bk, ck, 0, 0, 0);
                        cv = __builtin_amdgcn_mfma_f32_16x16x32_f16(af, bv, cv, 0, 0, 0);
                    }
                    const float bk_b = bkv[cb + nt*16 + lr];
                    const float bv_b = bkv[128 + cb + nt*16 + lr];
                    #pragma unroll
                    for (int e = 0; e < 4; ++e) {
                        const int row = mb + lg*4 + e;
                        kl[row * KS + nt*16 + lr] = (f16)(ck[e] + bk_b);
                        vt[(nt*16 + lr) * VTS + row] = (f16)(cv[e] + bv_b);
                    }
                }
            }
            #pragma unroll
            for (int mi = 0; mi < 2; ++mi) {
                const int qm = wv * 2 + mi;
                const int v_ = qm >> 2;
                const int hb = v_ * 96 + ((t == 0) ? 0 : 32) + (qm & 3) * 16;
                const int qb = v_ * 64 + (qm & 3) * 16;
                #pragma unroll
                for (int nt = 0; nt < 2; ++nt) {
                    f32x4 cq = {0.f,0.f,0.f,0.f};
                    #pragma unroll
                    for (int ks = 0; ks < 2; ++ks) {
                        const f16x8 af = *(const f16x8*)(hl + (hb + lr) * HLS + ks*32 + lg*8);
                        const f16x8 bq = *(const f16x8*)(WqF + (cb + nt*16 + lr)*64 + ks*32 + lg*8);
                        cq = __builtin_amdgcn_mfma_f32_16x16x32_f16(af, bq, cq, 0, 0, 0);
                    }
                    #pragma unroll
                    for (int e = 0; e < 4; ++e)
                        ql[(qb + lg*4 + e) * QLS + nt*16 + lr] = (f16)cq[e];
                }
            }
        }
        __syncthreads();   // kl/vt/ql ready for this head

        // per-row virtual zero-token weight
        float pz = 0.f;
        if (tid < 128) {
            const f16x2* qr2 = (const f16x2*)(ql + tid * QLS);
            float sz = 0.f;
            #pragma unroll
            for (int j = 0; j < 16; ++j)
                sz += (float)qr2[j].x * bkv[cb + 2*j] + (float)qr2[j].y * bkv[cb + 2*j + 1];
            pz = exp2fast(fmaf(sz, C1, CZV));
        }

        f32x4 oc00 = {0.f,0.f,0.f,0.f}, oc01 = {0.f,0.f,0.f,0.f};
        f32x4 oc10 = {0.f,0.f,0.f,0.f}, oc11 = {0.f,0.f,0.f,0.f};
        float l_own = 0.f;

        #pragma unroll 1
        for (int kk = 0; kk < 6; ++kk) {
            #pragma unroll
            for (int mi = 0; mi < 2; ++mi) {
                const f16x8 af = *(const f16x8*)(ql + (mA + mi*16 + lr) * QLS + lg * 8);
                #pragma unroll
                for (int nt = 0; nt < 2; ++nt) {
                    const f16x8 bf = *(const f16x8*)(kl + (kk*32 + nt*16 + lr) * KS + lg * 8);
                    const f32x4 c = __builtin_amdgcn_mfma_f32_16x16x32_f16(af, bf, (f32x4){0.f,0.f,0.f,0.f}, 0, 0, 0);
                    #pragma unroll
                    for (int e = 0; e < 4; ++e)
                        Pw[(mi*16 + lg*4 + e) * PSW + nt*16 + lr] = (f16)exp2fast(fmaf(c[e], C1, CZN));
                }
            }
            const f16x8 a0 = *(const f16x8*)(Pw + lr * PSW + lg * 8);
            const f16x8 a1 = *(const f16x8*)(Pw + (16 + lr) * PSW + lg * 8);
            const f16x8 b0 = *(const f16x8*)(vt + lr * VTS + kk*32 + lg*8);
            const f16x8 b1 = *(const f16x8*)(vt + (16 + lr) * VTS + kk*32 + lg*8);
            oc00 = __builtin_amdgcn_mfma_f32_16x16x32_f16(a0, b0, oc00, 0, 0, 0);
            oc01 = __builtin_amdgcn_mfma_f32_16x16x32_f16(a0, b1, oc01, 0, 0, 0);
            oc10 = __builtin_amdgcn_mfma_f32_16x16x32_f16(a1, b0, oc10, 0, 0, 0);
            oc11 = __builtin_amdgcn_mfma_f32_16x16x32_f16(a1, b1, oc11, 0, 0, 0);
            {
                const f16x2* pr = (const f16x2*)(Pw + prow * PSW + pcolh * 16);
                const f16x2 ones = (f16x2){(f16)1.f, (f16)1.f};
                float sa = 0.f, sb = 0.f;
                #pragma unroll
                for (int q = 0; q < 4; ++q) { sa = fdot2f(pr[2*q], ones, sa); sb = fdot2f(pr[2*q+1], ones, sb); }
                l_own += sa + sb;
            }
        }

        l_own += __shfl_xor(l_own, 32);
        if (lane < 32) linv[mA + lane] = l_own;
        __syncthreads();
        if (tid < 128) {
            const float inv = 1.0f / (linv[tid] + pz);
            linv[tid] = inv;
            pzn[tid]  = pz * inv;
        }
        __syncthreads();

        #define EPI_TILE(CC, MI, NI) { \
            const int ch = (NI) * 16 + lr; \
            const float bv = bkv[128 + cb + ch]; \
            _Pragma("unroll") \
            for (int e = 0; e < 4; ++e) { \
                const int row = mA + (MI) * 16 + lg * 4 + e; \
                const float oo = fmaf(pzn[row], bv, CC[e] * linv[row]); \
                const int v2 = row >> 6, tt2 = (row >> 4) & 3, nn2 = (row >> 2) & 3, dd2 = row & 3; \
                const size_t tk = ((size_t)(v2 * 8 + t * 4 + tt2) * 1024 + n * 4 + nn2) * 4 + dd2; \
                o_out[tk * 128 + cb + ch] = (f16)oo; \
            } }
        EPI_TILE(oc00, 0, 0)
        EPI_TILE(oc01, 0, 1)
        EPI_TILE(oc10, 1, 0)
        EPI_TILE(oc11, 1, 1)
        #undef EPI_TILE
        __syncthreads();   // linv/pzn reads done; next head may redo C / flash
    }
}

// ---------------- Kernel 2: MFMA epilogue, 64 tokens/block (r17, unchanged) ----------------
__global__ __launch_bounds__(256, 3) void k_epi(
    const float* __restrict__ x, const f16* __restrict__ o_in,
    const float* __restrict__ bo, const float* __restrict__ gamma,
    const float* __restrict__ ln2_s, const float* __restrict__ ln2_b,
    const float* __restrict__ b1, const float* __restrict__ b2,
    const float* __restrict__ gm, float* __restrict__ out)
{
    __shared__ __align__(16) char smem[EPI_LDS];
    f16* eol    = (f16*)(smem + OFF_EOL);
    float* etv  = (float*)(smem + OFF_ETV);
    f16* eh2    = (f16*)(smem + OFF_EH2);
    float* erd  = (float*)(smem + OFF_ERD);
    f16* ehid   = eol;

    const f16* WoF = (const f16*)(g_wpack + OFF_WO);
    const f16* W1F = (const f16*)(g_wpack + OFF_W1);
    const f16* W2F = (const f16*)(g_wpack + OFF_W2);

    const int tid = threadIdx.x;
    const int lane = tid & 63, wv = tid >> 6;
    const int lr = lane & 15, lg = lane >> 4;
    const int mb = wv * 16;
    const size_t tok0 = (size_t)blockIdx.x * 64;

    {   // Phase A: coalesced o -> LDS; 32 f16 (64B) per thread = full tile
        const int tk = tid >> 2, part = tid & 3;
        const f16x8* src = (const f16x8*)(o_in + (tok0 + tk) * 128 + part * 32);
        f16x8* dst = (f16x8*)(eol + tk * EOLS + part * 32);
        dst[0] = src[0]; dst[1] = src[1]; dst[2] = src[2]; dst[3] = src[3];
    }
    __syncthreads();

    {   // Phase B: upd = o @ Wo (MFMA, K=128); fused residual -> tv
        f16x8 a_[4];
        #pragma unroll
        for (int ks = 0; ks < 4; ++ks)
            a_[ks] = *(const f16x8*)(eol + (mb + lr) * EOLS + ks*32 + lg*8);
        #pragma unroll
        for (int nt = 0; nt < 4; ++nt) {
            const int ch = nt * 16 + lr;
            f32x4 c = {0.f,0.f,0.f,0.f};
            c = __builtin_amdgcn_mfma_f32_16x16x32_f16(a_[0], *(const f16x8*)(WoF + ch*128 +  0 + lg*8), c, 0, 0, 0);
            c = __builtin_amdgcn_mfma_f32_16x16x32_f16(a_[1], *(const f16x8*)(WoF + ch*128 + 32 + lg*8), c, 0, 0, 0);
            c = __builtin_amdgcn_mfma_f32_16x16x32_f16(a_[2], *(const f16x8*)(WoF + ch*128 + 64 + lg*8), c, 0, 0, 0);
            c = __builtin_amdgcn_mfma_f32_16x16x32_f16(a_[3], *(const f16x8*)(WoF + ch*128 + 96 + lg*8), c, 0, 0, 0);
            const float bo_c = bo[ch], ga_c = gamma[ch];
            #pragma unroll
            for (int e = 0; e < 4; ++e) {
                const int tk = mb + lg*4 + e;
                etv[tk * ETVS + ch] = x[(tok0 + tk)*64 + ch] + ga_c * (c[e] + bo_c);
            }
        }
    }
    __syncthreads();

    {   // Phase C1: LN2 partial stats (4 threads/token)
        const int tk = tid >> 2, q = tid & 3;
        const float* tr = etv + tk * ETVS + q * 16;
        float s1 = 0.f, s2 = 0.f;
        #pragma unroll
        for (int j = 0; j < 16; ++j) { const float v = tr[j]; s1 += v; s2 += v*v; }
        erd[(tk*4 + q)*2] = s1; erd[(tk*4 + q)*2 + 1] = s2;
    }
    __syncthreads();
    {   // Phase C2: finalize LN2 -> eh2 (f16)
        const int tk = tid >> 2, q = tid & 3;
        float a1 = 0.f, a2 = 0.f;
        #pragma unroll
        for (int i = 0; i < 4; ++i) { a1 += erd[(tk*4 + i)*2]; a2 += erd[(tk*4 + i)*2 + 1]; }
        const float mean = a1 * 0.015625f;
        const float rstd = rsqrtf(a2 * 0.015625f - mean*mean + 1e-5f);
        const float* tr = etv + tk * ETVS + q * 16;
        f16* hr = eh2 + tk * EH2S + q * 16;
        #pragma unroll
        for (int j = 0; j < 16; ++j)
            hr[j] = (f16)((tr[j]-mean)*rstd*ln2_s[q*16 + j] + ln2_b[q*16 + j]);
    }
    __syncthreads();

    {   // Phase D: hid = gelu(h2 @ W1) (MFMA, K=64); hid overlays dead o buffer.
        f16x8 a_[2];
        #pragma unroll
        for (int ks = 0; ks < 2; ++ks)
            a_[ks] = *(const f16x8*)(eh2 + (mb + lr) * EH2S + ks*32 + lg*8);
        #pragma unroll
        for (int nt = 0; nt < 8; ++nt) {
            const int ch = nt * 16 + lr;
            f32x4 c = {0.f,0.f,0.f,0.f};
            c = __builtin_amdgcn_mfma_f32_16x16x32_f16(a_[0], *(const f16x8*)(W1F + ch*64 +  0 + lg*8), c, 0, 0, 0);
            c = __builtin_amdgcn_mfma_f32_16x16x32_f16(a_[1], *(const f16x8*)(W1F + ch*64 + 32 + lg*8), c, 0, 0, 0);
            const float b1_c = b1[ch];
            #pragma unroll
            for (int e = 0; e < 4; ++e) {
                const int tk = mb + lg*4 + e;
                const float z = c[e] + b1_c;
                const float u = 0.7978845608028654f * (z + 0.044715f * z*z*z);
                ehid[tk * EOLS + ch] = (f16)(z / (1.0f + exp2fast(-2.8853900817779268f * u)));
            }
        }
    }
    __syncthreads();

    {   // Phase E: oa = hid @ W2 (MFMA, K=128); final residual -> out
        f16x8 a_[4];
        #pragma unroll
        for (int ks = 0; ks < 4; ++ks)
            a_[ks] = *(const f16x8*)(ehid + (mb + lr) * EOLS + ks*32 + lg*8);
        #pragma unroll
        for (int nt = 0; nt < 4; ++nt) {
            const int ch = nt * 16 + lr;
            f32x4 c = {0.f,0.f,0.f,0.f};
            c = __builtin_amdgcn_mfma_f32_16x16x32_f16(a_[0], *(const f16x8*)(W2F + ch*128 +  0 + lg*8), c, 0, 0, 0);
            c = __builtin_amdgcn_mfma_f32_16x16x32_f16(a_[1], *(const f16x8*)(W2F + ch*128 + 32 + lg*8), c, 0, 0, 0);
            c = __builtin_amdgcn_mfma_f32_16x16x32_f16(a_[2], *(const f16x8*)(W2F + ch*128 + 64 + lg*8), c, 0, 0, 0);
            c = __builtin_amdgcn_mfma_f32_16x16x32_f16(a_[3], *(const f16x8*)(W2F + ch*128 + 96 + lg*8), c, 0, 0, 0);
            const float b2_c = b2[ch], gm_c = gm[ch];
            #pragma unroll
            for (int e = 0; e < 4; ++e) {
                const int tk = mb + lg*4 + e;
                out[(tok0 + tk)*64 + ch] = etv[tk * ETVS + ch] + gm_c * (c[e] + b2_c);
            }
        }
    }
}

extern "C" void kernel_launch(void* const* d_in, const int* in_sizes, int n_in,
                              void* d_out, int out_size, void* d_ws, size_t ws_size,
                              hipStream_t stream) {
    const float* x        = (const float*)d_in[0];
    const float* ln1_s    = (const float*)d_in[1];
    const float* ln1_b    = (const float*)d_in[2];
    const float* Wq       = (const float*)d_in[3];
    const float* Wkv      = (const float*)d_in[4];
    const float* bkv      = (const float*)d_in[5];
    const float* Wo       = (const float*)d_in[6];
    const float* bo       = (const float*)d_in[7];
    const float* gamma    = (const float*)d_in[8];
    const float* ln2_s    = (const float*)d_in[9];
    const float* ln2_b    = (const float*)d_in[10];
    const float* W1       = (const float*)d_in[11];
    const float* b1       = (const float*)d_in[12];
    const float* W2       = (const float*)d_in[13];
    const float* b2       = (const float*)d_in[14];
    const float* gamma_mlp= (const float*)d_in[15];

    // o (f16[65536][128]) aliases d_out (f32[65536][64]); disjoint token partition
    // between k_att writes and k_epi reads/overwrites -> race-free.
    f16* o_buf = (f16*)d_out;
    float* out = (float*)d_out;

    hipLaunchKernelGGL(k_conv, dim3(NPAIRS / 256), dim3(256), 0, stream,
                       Wq, Wkv, Wo, W1, W2);
    hipLaunchKernelGGL(k_att, dim3(512), dim3(256), 0, stream,
                       x, ln1_s, ln1_b, bkv, o_buf);
    hipLaunchKernelGGL(k_epi, dim3(1024), dim3(256), 0, stream,
                       x, o_buf, bo, gamma, ln2_s, ln2_b, b1, b2, gamma_mlp, out);
}